// Round 12
// baseline (528.498 us; speedup 1.0000x reference)
//
#include <hip/hip_runtime.h>
#include <cstdio>

#define D_ 256
#define LT 1024
#define LA 2048
#define NB 16
#define RR_ 64
#define NRT (NB*LT)   // 16384 text rows
#define NRA (NB*LA)   // 32768 audio rows

// logK u8 quantization: q = rint((1-cos)*124), logK_hat = q * DECQ (nat log)
// exp2 domain: DECQ2 = DECQ * log2(e)
#define DECQ  (-0.080645161f)
#define DECQ2 (-0.11634637f)

typedef short bf16x8 __attribute__((ext_vector_type(8)));
typedef float f32x4 __attribute__((ext_vector_type(4)));

__device__ __forceinline__ float gelu_f(float x) {
    return 0.5f * x * (1.0f + erff(x * 0.70710678118654752f));
}
__device__ __forceinline__ unsigned short f2bf(float f) {   // RNE
    union { float f; unsigned int i; } c; c.f = f;
    unsigned int x = c.i;
    return (unsigned short)((x + 0x7fffu + ((x >> 16) & 1u)) >> 16);
}
__device__ __forceinline__ float bf2f(unsigned short u) {
    return __uint_as_float((unsigned int)u << 16);
}
// raw v_exp_f32: args here are always > -126, so no denormal fixup needed
__device__ __forceinline__ float exp2_fast(float x) {
#if __has_builtin(__builtin_amdgcn_exp2f)
    return __builtin_amdgcn_exp2f(x);
#else
    float r; asm("v_exp_f32 %0, %1" : "=v"(r) : "v"(x)); return r;
#endif
}
// pack 2 f32 -> 2 bf16 (RNE) in one instruction; lo = first arg
__device__ __forceinline__ unsigned int cvt_pk_bf16(float lo, float hi) {
    unsigned int r;
    asm("v_cvt_pk_bf16_f32 %0, %1, %2" : "=v"(r) : "v"(lo), "v"(hi));
    return r;
}

// ---------------- prep: all weight fp32->bf16 conversions in ONE launch ----------------
__global__ __launch_bounds__(256) void k_prep_all(
    const float* __restrict__ W_sh, const float* __restrict__ down_W,
    const float* __restrict__ up_W, const float* __restrict__ Wr1,
    unsigned short* __restrict__ Wb, unsigned short* __restrict__ dWb,
    unsigned short* __restrict__ uWb, unsigned short* __restrict__ Wr1b)
{
    int i = blockIdx.x * 256 + threadIdx.x;          // 0 .. 229375
    if (i < 65536) Wb[i] = f2bf(W_sh[i]);
    else if (i < 114688) { int j = i - 65536; dWb[j] = f2bf(down_W[j]); }
    else if (i < 163840) { int j = i - 114688; uWb[j] = f2bf(up_W[j]); }
    else { int j = i - 163840; int n = j >> 8, k = j & 255; Wr1b[j] = f2bf(Wr1[(long)n * 257 + 1 + k]); }
}

// ---------------- K1: LayerNorm + shared projection (MFMA), text+audio fused ----------------
// blocks [0, 256): text rows -> Tp + Tnb.  blocks [256, 768): audio rows -> Anb + ApbT
// (ApbT emitted via in-kernel LDS transpose, aliasing the dead xb/Bs buffers).
// r8-proven structure: W staged through LDS (Bs), 2 barriers per K-step.
__global__ __launch_bounds__(256) void k_lnproj_fused(
    const float* __restrict__ Xt, const float* __restrict__ Xa,
    const float* __restrict__ g, const float* __restrict__ bln,
    const unsigned short* __restrict__ Wb, const float* __restrict__ bsh,
    float* __restrict__ Tp, unsigned short* __restrict__ Tnb,
    unsigned short* __restrict__ Anb, unsigned short* __restrict__ ApbT)
{
    __shared__ short smem[64 * 264 + 256 * 40];          // 54272 B
    short (*xb)[264] = (short(*)[264])smem;
    short (*Bs)[40]  = (short(*)[40])(smem + 64 * 264);
    short (*tt)[72]  = (short(*)[72])smem;               // 36864 B, aliases xb+Bs (dead post-loop)
    int tid = threadIdx.x;
    int bid = blockIdx.x;
    bool is_text = bid < (NRT / 64);
    const float* X = is_text ? Xt : Xa;
    long row0 = is_text ? (long)bid * 64 : (long)(bid - NRT / 64) * 64;
    {
        int lane = tid & 31, rg = tid >> 5;
        float4 ga = *(const float4*)(g + lane * 8);
        float4 gb2 = *(const float4*)(g + lane * 8 + 4);
        float4 ba = *(const float4*)(bln + lane * 8);
        float4 bb2 = *(const float4*)(bln + lane * 8 + 4);
        for (int it = 0; it < 8; it++) {
            int r = it * 8 + rg;
            const float4* xp4 = (const float4*)(X + (row0 + r) * D_);
            float4 a = xp4[lane * 2], b = xp4[lane * 2 + 1];
            float s = a.x + a.y + a.z + a.w + b.x + b.y + b.z + b.w;
#pragma unroll
            for (int off = 16; off >= 1; off >>= 1) s += __shfl_xor(s, off);
            float mean = s * (1.0f / 256.0f);
            float q = (a.x - mean) * (a.x - mean) + (a.y - mean) * (a.y - mean)
                    + (a.z - mean) * (a.z - mean) + (a.w - mean) * (a.w - mean)
                    + (b.x - mean) * (b.x - mean) + (b.y - mean) * (b.y - mean)
                    + (b.z - mean) * (b.z - mean) + (b.w - mean) * (b.w - mean);
#pragma unroll
            for (int off = 16; off >= 1; off >>= 1) q += __shfl_xor(q, off);
            float ivar = rsqrtf(q * (1.0f / 256.0f) + 1e-5f);
            float v0 = (a.x - mean) * ivar * ga.x + ba.x;
            float v1 = (a.y - mean) * ivar * ga.y + ba.y;
            float v2 = (a.z - mean) * ivar * ga.z + ba.z;
            float v3 = (a.w - mean) * ivar * ga.w + ba.w;
            float v4 = (b.x - mean) * ivar * gb2.x + bb2.x;
            float v5 = (b.y - mean) * ivar * gb2.y + bb2.y;
            float v6 = (b.z - mean) * ivar * gb2.z + bb2.z;
            float v7 = (b.w - mean) * ivar * gb2.w + bb2.w;
            int4 pv;
            pv.x = (int)cvt_pk_bf16(v0, v1); pv.y = (int)cvt_pk_bf16(v2, v3);
            pv.z = (int)cvt_pk_bf16(v4, v5); pv.w = (int)cvt_pk_bf16(v6, v7);
            *(int4*)&xb[r][lane * 8] = pv;
        }
    }
    __syncthreads();
    int wid = tid >> 6, lane = tid & 63;
    int l15 = lane & 15, kq = lane >> 4;
    int m_local = wid * 16;
    f32x4 acc[16];
#pragma unroll
    for (int j = 0; j < 16; j++) acc[j] = (f32x4){0.f, 0.f, 0.f, 0.f};
    for (int kt = 0; kt < 8; kt++) {
        int k0 = kt * 32;
#pragma unroll
        for (int h = 0; h < 4; h++) {
            int idx = tid + 256 * h;
            int n = idx >> 2, qc = idx & 3;
            *(int4*)&Bs[n][qc * 8] = *(const int4*)(Wb + (long)n * D_ + k0 + qc * 8);
        }
        __syncthreads();
        bf16x8 af = *(const bf16x8*)&xb[m_local + l15][k0 + kq * 8];
#pragma unroll
        for (int j = 0; j < 16; j++) {
            bf16x8 bf = *(const bf16x8*)&Bs[j * 16 + l15][kq * 8];
            acc[j] = __builtin_amdgcn_mfma_f32_16x16x32_bf16(af, bf, acc[j], 0, 0, 0);
        }
        __syncthreads();
    }
#pragma unroll
    for (int j = 0; j < 16; j++) {
        float bv = bsh[j * 16 + l15];
#pragma unroll
        for (int r = 0; r < 4; r++) acc[j][r] += bv;
    }
    float sq[4] = {0.f, 0.f, 0.f, 0.f};
#pragma unroll
    for (int j = 0; j < 16; j++)
#pragma unroll
        for (int r = 0; r < 4; r++) sq[r] += acc[j][r] * acc[j][r];
#pragma unroll
    for (int off = 8; off >= 1; off >>= 1) {
#pragma unroll
        for (int r = 0; r < 4; r++) sq[r] += __shfl_xor(sq[r], off);
    }
    float rinv[4];
#pragma unroll
    for (int r = 0; r < 4; r++) rinv[r] = 1.0f / fmaxf(sqrtf(sq[r]), 1e-12f);
    if (is_text) {
#pragma unroll
        for (int j = 0; j < 16; j++) {
            int col = j * 16 + l15;
#pragma unroll
            for (int r = 0; r < 4; r++) {
                long m = row0 + m_local + kq * 4 + r;
                Tp[m * D_ + col] = acc[j][r];
                Tnb[m * D_ + col] = f2bf(acc[j][r] * rinv[r]);
            }
        }
    } else {
        // write Anb row-major + stage normalized tile into LDS for ApbT transpose.
        // tt aliases xb/Bs: both are dead after the K-loop's final __syncthreads.
#pragma unroll
        for (int j = 0; j < 16; j++) {
            int col = j * 16 + l15;
#pragma unroll
            for (int r = 0; r < 4; r++) {
                int rloc = m_local + kq * 4 + r;
                unsigned short qv = f2bf(acc[j][r] * rinv[r]);
                Anb[(row0 + rloc) * D_ + col] = qv;
                tt[col][rloc] = (short)qv;
            }
        }
        __syncthreads();
        int b = (int)(row0 >> 11);           // LA = 2048
        int n0 = (int)(row0 & 2047);
#pragma unroll
        for (int h = 0; h < 8; h++) {
            int ci = tid + 256 * h;          // 2048 int4 chunks
            int col = ci >> 3, nch = ci & 7;
            int4 v = *(const int4*)&tt[col][nch * 8];
            *(int4*)(ApbT + ((long)b * D_ + col) * LA + n0 + nch * 8) = v;
        }
    }
}

// ---------------- K2: cost GEMM (MFMA bf16) -> logK u8 + transposed logK8T ----------------
__global__ __launch_bounds__(256) void k_cost_mfma(
    const unsigned short* __restrict__ Tnb, const unsigned short* __restrict__ Anb,
    unsigned char* __restrict__ logK8, unsigned char* __restrict__ logK8T)
{
    __shared__ short sm[2][128][48];
    short (*As)[48] = sm[0];
    short (*Bs)[48] = sm[1];
    unsigned char* tile = (unsigned char*)sm;
    int b = blockIdx.x;
    int m_blk = blockIdx.y * 128, n_blk = blockIdx.z * 128;
    int tid = threadIdx.x;
    int wid = tid >> 6, lane = tid & 63;
    int l15 = lane & 15, kq = lane >> 4;
    int wm0 = (wid >> 1) * 64, wn0 = (wid & 1) * 64;
    const unsigned short* Ab = Tnb + ((long)b * LT + m_blk) * D_;
    const unsigned short* Bb = Anb + ((long)b * LA + n_blk) * D_;
    f32x4 acc[4][4];
#pragma unroll
    for (int i = 0; i < 4; i++)
#pragma unroll
        for (int j = 0; j < 4; j++) acc[i][j] = (f32x4){0.f, 0.f, 0.f, 0.f};
    for (int kt = 0; kt < 8; kt++) {
        int k0 = kt * 32;
#pragma unroll
        for (int h = 0; h < 2; h++) {
            int idx = tid + 256 * h;
            int row = idx >> 2, ch = idx & 3;
            *(int4*)&As[row][ch * 8] = *(const int4*)(Ab + (long)row * D_ + k0 + ch * 8);
            *(int4*)&Bs[row][ch * 8] = *(const int4*)(Bb + (long)row * D_ + k0 + ch * 8);
        }
        __syncthreads();
        bf16x8 af[4], bfv[4];
#pragma unroll
        for (int i = 0; i < 4; i++) af[i] = *(const bf16x8*)&As[wm0 + i * 16 + l15][kq * 8];
#pragma unroll
        for (int j = 0; j < 4; j++) bfv[j] = *(const bf16x8*)&Bs[wn0 + j * 16 + l15][kq * 8];
#pragma unroll
        for (int i = 0; i < 4; i++)
#pragma unroll
            for (int j = 0; j < 4; j++)
                acc[i][j] = __builtin_amdgcn_mfma_f32_16x16x32_bf16(af[i], bfv[j], acc[i][j], 0, 0, 0);
        __syncthreads();
    }
    // quantize once: direct row-major byte stores + packed u32 into transpose tile
#pragma unroll
    for (int i = 0; i < 4; i++) {
#pragma unroll
        for (int j = 0; j < 4; j++) {
            int n = wn0 + j * 16 + l15;                       // n_local
            long base = ((long)b * LT + m_blk + wm0 + i * 16 + kq * 4) * (long)LA + n_blk + n;
            unsigned int pk = 0;
#pragma unroll
            for (int r = 0; r < 4; r++) {
                float q = rintf((1.0f - acc[i][j][r]) * 124.0f);
                q = fminf(fmaxf(q, 0.0f), 255.0f);
                unsigned int qb = (unsigned int)q;
                pk |= qb << (8 * r);
                logK8[base + (long)r * LA] = (unsigned char)qb;
            }
            *(unsigned int*)&tile[n * 144 + wm0 + i * 16 + kq * 4] = pk;
        }
    }
    __syncthreads();
#pragma unroll
    for (int h = 0; h < 4; h++) {
        int idx = tid + 256 * h;
        int row = idx >> 3, ch = idx & 7;                    // 128 n-rows x 8 int4 chunks
        int4 v = *(const int4*)&tile[row * 144 + ch * 16];
        *(int4*)(logK8T + ((long)b * LA + n_blk + row) * (long)LT + m_blk + ch * 16) = v;
    }
}

// ---------------- K3: row LSE, 8 rows/block, lv slice in regs reused 4x ----------------
__global__ __launch_bounds__(256) void k_rowlse4(
    const unsigned char* __restrict__ logK8, const float* __restrict__ lv2,
    float* __restrict__ lu2, int first)
{
    __shared__ float red[8][2];
    int b = blockIdx.x & 15;
    int mseg = blockIdx.x >> 4;          // 0..127, 8 rows each
    int tid = threadIdx.x;
    int rg = tid >> 7;                   // 0..1 row group
    int ln = tid & 127;                  // lane within row (x16 bytes)
    float lvv[16];
    if (!first) {
        const float* lvp = lv2 + (long)b * LA + ln * 16;
#pragma unroll
        for (int k = 0; k < 4; k++) {
            float4 l = *(const float4*)(lvp + k * 4);
            lvv[k * 4 + 0] = l.x; lvv[k * 4 + 1] = l.y;
            lvv[k * 4 + 2] = l.z; lvv[k * 4 + 3] = l.w;
        }
    } else {
#pragma unroll
        for (int k = 0; k < 16; k++) lvv[k] = 0.f;
    }
    const unsigned char* p = logK8 + ((long)b * LT + mseg * 8 + rg * 4) * (long)LA + ln * 16;
#pragma unroll
    for (int r = 0; r < 4; r++) {
        uint4 w = *(const uint4*)(p + (long)r * LA);
        unsigned int ws4[4] = {w.x, w.y, w.z, w.w};
        float s = 0.f;
#pragma unroll
        for (int k = 0; k < 4; k++) {
            unsigned int u = ws4[k];
            s += exp2_fast(fmaf((float)(u & 0xffu),         DECQ2, lvv[k * 4 + 0]));
            s += exp2_fast(fmaf((float)((u >> 8) & 0xffu),  DECQ2, lvv[k * 4 + 1]));
            s += exp2_fast(fmaf((float)((u >> 16) & 0xffu), DECQ2, lvv[k * 4 + 2]));
            s += exp2_fast(fmaf((float)(u >> 24),           DECQ2, lvv[k * 4 + 3]));
        }
#pragma unroll
        for (int off = 32; off >= 1; off >>= 1) s += __shfl_xor(s, off);
        if ((tid & 63) == 0) red[rg * 4 + r][(tid >> 6) & 1] = s;
    }
    __syncthreads();
    if (tid < 8) {
        float sr = red[tid][0] + red[tid][1];
        lu2[(long)b * LT + mseg * 8 + tid] = -10.0f - __log2f(sr);   // -log2(Lt) - log2(s)
    }
}

// ---------------- K4: col LSE over logK8T, 16 cols/block, lu slice in regs reused 4x ----------
__global__ __launch_bounds__(256) void k_collse4(
    const unsigned char* __restrict__ logK8T, const float* __restrict__ lu2,
    float* __restrict__ lv2)
{
    int b = blockIdx.x & 15;
    int nseg = blockIdx.x >> 4;          // 0..127, 16 cols each
    int tid = threadIdx.x;
    int wv = tid >> 6, lane = tid & 63;
    float lus[16];
    const float* lup = lu2 + (long)b * LT + lane * 16;
#pragma unroll
    for (int k = 0; k < 4; k++) {
        float4 l = *(const float4*)(lup + k * 4);
        lus[k * 4 + 0] = l.x; lus[k * 4 + 1] = l.y;
        lus[k * 4 + 2] = l.z; lus[k * 4 + 3] = l.w;
    }
    const unsigned char* p = logK8T + ((long)b * LA + nseg * 16 + wv * 4) * (long)LT + lane * 16;
#pragma unroll
    for (int cs = 0; cs < 4; cs++) {
        uint4 w = *(const uint4*)(p + (long)cs * LT);
        unsigned int ws4[4] = {w.x, w.y, w.z, w.w};
        float s = 0.f;
#pragma unroll
        for (int k = 0; k < 4; k++) {
            unsigned int u = ws4[k];
            s += exp2_fast(fmaf((float)(u & 0xffu),         DECQ2, lus[k * 4 + 0]));
            s += exp2_fast(fmaf((float)((u >> 8) & 0xffu),  DECQ2, lus[k * 4 + 1]));
            s += exp2_fast(fmaf((float)((u >> 16) & 0xffu), DECQ2, lus[k * 4 + 2]));
            s += exp2_fast(fmaf((float)(u >> 24),           DECQ2, lus[k * 4 + 3]));
        }
#pragma unroll
        for (int off = 32; off >= 1; off >>= 1) s += __shfl_xor(s, off);
        if (lane == 0)
            lv2[(long)b * LA + nseg * 16 + wv * 4 + cs] = -11.0f - __log2f(s);
    }
}

// ---------------- K5: A_al = eu * ((F*ev) @ Ap); bf16 output, K-split x2 (r10 proven) --------
__global__ __launch_bounds__(256) void k_pi2(
    const unsigned char* __restrict__ logK8, const unsigned short* __restrict__ Ap,
    const float* __restrict__ lu2, const float* __restrict__ lv2,
    unsigned short* __restrict__ Apart)
{
    __shared__ short As[64][56];       // stride 112B = 28 dw: rows r,r+8 alias -> free 2-way only
    __shared__ short Bs[256][56];
    __shared__ float lv_s[1024];
    __shared__ float eus[64];
    int b = blockIdx.x;
    int kh = blockIdx.y;               // 0..1: half of the n axis
    int m_blk = blockIdx.z * 64;
    int nbase = kh * 1024;
    int tid = threadIdx.x;
    for (int i = tid; i < 1024; i += 256) lv_s[i] = lv2[(long)b * LA + nbase + i];
    if (tid < 64) eus[tid] = exp2_fast(lu2[(long)b * LT + m_blk + tid]);
    __syncthreads();
    int wid = tid >> 6, lane = tid & 63;
    int l15 = lane & 15, kq = lane >> 4;
    int wm0 = (wid & 1) * 32, wd0 = (wid >> 1) * 128;
    f32x4 acc[2][8];
#pragma unroll
    for (int i = 0; i < 2; i++)
#pragma unroll
        for (int j = 0; j < 8; j++) acc[i][j] = (f32x4){0.f, 0.f, 0.f, 0.f};
    const unsigned char* Kbase = logK8 + ((long)b * LT + m_blk) * (long)LA + nbase;
    const unsigned short* Bbase = Ap + (long)b * D_ * (long)LA + nbase;
    int arow = tid >> 2, ac8 = (tid & 3) * 8;
    for (int kt = 0; kt < 32; kt++) {
        int n0 = kt * 32;
        {
            uint2 raw = *(const uint2*)(Kbase + (long)arow * LA + n0 + ac8);
            const float* lvp = &lv_s[n0 + ac8];
            unsigned int w0 = raw.x, w1 = raw.y;
            float e0 = exp2_fast(fmaf((float)(w0 & 0xffu),         DECQ2, lvp[0]));
            float e1 = exp2_fast(fmaf((float)((w0 >> 8) & 0xffu),  DECQ2, lvp[1]));
            float e2 = exp2_fast(fmaf((float)((w0 >> 16) & 0xffu), DECQ2, lvp[2]));
            float e3 = exp2_fast(fmaf((float)(w0 >> 24),           DECQ2, lvp[3]));
            float e4 = exp2_fast(fmaf((float)(w1 & 0xffu),         DECQ2, lvp[4]));
            float e5 = exp2_fast(fmaf((float)((w1 >> 8) & 0xffu),  DECQ2, lvp[5]));
            float e6 = exp2_fast(fmaf((float)((w1 >> 16) & 0xffu), DECQ2, lvp[6]));
            float e7 = exp2_fast(fmaf((float)(w1 >> 24),           DECQ2, lvp[7]));
            int4 ov;
            ov.x = (int)cvt_pk_bf16(e0, e1); ov.y = (int)cvt_pk_bf16(e2, e3);
            ov.z = (int)cvt_pk_bf16(e4, e5); ov.w = (int)cvt_pk_bf16(e6, e7);
            *(int4*)&As[arow][ac8] = ov;
        }
#pragma unroll
        for (int h = 0; h < 4; h++) {
            int idx = tid + 256 * h;
            int row = idx >> 2, ch = idx & 3;
            *(int4*)&Bs[row][ch * 8] = *(const int4*)(Bbase + (long)row * LA + n0 + ch * 8);
        }
        __syncthreads();
        bf16x8 af[2], bfv[8];
        af[0] = *(const bf16x8*)&As[wm0 + l15][kq * 8];
        af[1] = *(const bf16x8*)&As[wm0 + 16 + l15][kq * 8];
#pragma unroll
        for (int j = 0; j < 8; j++) bfv[j] = *(const bf16x8*)&Bs[wd0 + j * 16 + l15][kq * 8];
#pragma unroll
        for (int i = 0; i < 2; i++)
#pragma unroll
            for (int j = 0; j < 8; j++)
                acc[i][j] = __builtin_amdgcn_mfma_f32_16x16x32_bf16(af[i], bfv[j], acc[i][j], 0, 0, 0);
        __syncthreads();
    }
    unsigned short* dst = Apart + (long)kh * (NB * (long)LT * D_);
#pragma unroll
    for (int i = 0; i < 2; i++) {
#pragma unroll
        for (int r = 0; r < 4; r++) {
            int rloc = wm0 + i * 16 + kq * 4 + r;
            float eu = eus[rloc];
            int m = m_blk + rloc;
            long obase = ((long)b * LT + m) * D_;
#pragma unroll
            for (int j = 0; j < 8; j++)
                dst[obase + wd0 + j * 16 + l15] = f2bf(acc[i][j][r] * eu);
        }
    }
}

// ---------------- K6: combine 2 bf16 K-halves, S, residb (batch-fastest) ----------------
__global__ __launch_bounds__(256) void k_sresid(
    const float* __restrict__ Tp, const unsigned short* __restrict__ Apart,
    unsigned short* __restrict__ residb, float* __restrict__ S)
{
    __shared__ float red[4];
    int b = blockIdx.x & 15;
    int m = blockIdx.x >> 4;
    long row = (long)b * LT + m;
    int tid = threadIdx.x;
    long idx = row * D_ + tid;
    float t = Tp[idx];
    float a = bf2f(Apart[idx]) + bf2f(Apart[idx + 1L * NB * LT * D_]);
    float rr = fabsf(t - a);
    residb[idx] = f2bf(rr);
    float p = t * a;
#pragma unroll
    for (int off = 32; off >= 1; off >>= 1) p += __shfl_xor(p, off);
    if ((tid & 63) == 0) red[tid >> 6] = p;
    __syncthreads();
    if (tid == 0) S[row] = red[0] + red[1] + red[2] + red[3];
}

// ---------------- K7: router fused, col-split waves: 16 rows/block ----------------
__global__ __launch_bounds__(256) void k_router_fused(
    const unsigned short* __restrict__ residb, const unsigned short* __restrict__ Wr1b,
    const float* __restrict__ Wr1, const float* __restrict__ br1,
    const float* __restrict__ S, const float* __restrict__ Wr2,
    const float* __restrict__ br2, float* __restrict__ G)
{
    __shared__ short xb[16][264];
    __shared__ short Bs[256][40];
    __shared__ float red[4][3][16];
    int tid = threadIdx.x;
    long row0 = (long)blockIdx.x * 16;
#pragma unroll
    for (int h = 0; h < 2; h++) {
        int idx = tid + 256 * h;
        int row = idx >> 5, ch = idx & 31;
        *(int4*)&xb[row][ch * 8] = *(const int4*)(residb + (row0 + row) * D_ + ch * 8);
    }
    __syncthreads();
    int wid = tid >> 6, lane = tid & 63;
    int l15 = lane & 15, kq = lane >> 4;
    f32x4 acc[4];
#pragma unroll
    for (int j = 0; j < 4; j++) acc[j] = (f32x4){0.f, 0.f, 0.f, 0.f};
    for (int kt = 0; kt < 8; kt++) {
        int k0 = kt * 32;
#pragma unroll
        for (int h = 0; h < 4; h++) {
            int idx = tid + 256 * h;
            int n = idx >> 2, qc = idx & 3;
            *(int4*)&Bs[n][qc * 8] = *(const int4*)(Wr1b + (long)n * D_ + k0 + qc * 8);
        }
        __syncthreads();
        bf16x8 af = *(const bf16x8*)&xb[l15][k0 + kq * 8];
#pragma unroll
        for (int j = 0; j < 4; j++) {
            bf16x8 bf = *(const bf16x8*)&Bs[wid * 64 + j * 16 + l15][kq * 8];
            acc[j] = __builtin_amdgcn_mfma_f32_16x16x32_bf16(af, bf, acc[j], 0, 0, 0);
        }
        __syncthreads();
    }
    float sv[4];
#pragma unroll
    for (int r = 0; r < 4; r++) sv[r] = S[row0 + kq * 4 + r];
    float le[3][4] = {};
#pragma unroll
    for (int j = 0; j < 4; j++) {
        int col = wid * 64 + j * 16 + l15;
        float w0 = Wr1[(long)col * 257];
        float bv = br1[col];
        float w2a = Wr2[col], w2b = Wr2[256 + col], w2c = Wr2[512 + col];
#pragma unroll
        for (int r = 0; r < 4; r++) {
            float hv = gelu_f(acc[j][r] + sv[r] * w0 + bv);
            le[0][r] += hv * w2a;
            le[1][r] += hv * w2b;
            le[2][r] += hv * w2c;
        }
    }
#pragma unroll
    for (int off = 8; off >= 1; off >>= 1)
#pragma unroll
        for (int e = 0; e < 3; e++)
#pragma unroll
            for (int r = 0; r < 4; r++) le[e][r] += __shfl_xor(le[e][r], off);
    if (l15 == 0) {
#pragma unroll
        for (int e = 0; e < 3; e++)
#pragma unroll
            for (int r = 0; r < 4; r++) red[wid][e][kq * 4 + r] = le[e][r];
    }
    __syncthreads();
    if (tid < 16) {
        float L0 = red[0][0][tid] + red[1][0][tid] + red[2][0][tid] + red[3][0][tid] + br2[0];
        float L1 = red[0][1][tid] + red[1][1][tid] + red[2][1][tid] + red[3][1][tid] + br2[1];
        float L2 = red[0][2][tid] + red[1][2][tid] + red[2][2][tid] + red[3][2][tid] + br2[2];
        float mx = fmaxf(L0, fmaxf(L1, L2));
        float e0 = __expf(L0 - mx), e1 = __expf(L1 - mx), e2 = __expf(L2 - mx);
        float inv = 1.0f / (e0 + e1 + e2);
        long m = row0 + tid;
        G[m] = e0 * inv; G[NRT + m] = e1 * inv; G[2 * NRT + m] = e2 * inv;
    }
}

// ---------------- K8a: h[e] = gelu(residb @ down_W[e]^T + down_b[e]) ----------------
__global__ __launch_bounds__(256) void k_down_mfma(
    const unsigned short* __restrict__ residb, const unsigned short* __restrict__ dWb,
    const float* __restrict__ db, float* __restrict__ hall)
{
    __shared__ short xb[64][264];
    __shared__ short Bs[64][40];
    int tid = threadIdx.x;
    int e = blockIdx.y;
    int b = blockIdx.x & 15;
    int mseg = blockIdx.x >> 4;
    long row0 = (long)b * LT + mseg * 64;
    const unsigned short* dWe = dWb + (long)e * RR_ * D_;
    float* h = hall + (long)e * NRT * RR_;
#pragma unroll
    for (int hh = 0; hh < 8; hh++) {
        int idx = tid + 256 * hh;
        int row = idx >> 5, ch = idx & 31;
        *(int4*)&xb[row][ch * 8] = *(const int4*)(residb + (row0 + row) * D_ + ch * 8);
    }
    __syncthreads();
    int wid = tid >> 6, lane = tid & 63;
    int l15 = lane & 15, kq = lane >> 4;
    int m_local = wid * 16;
    f32x4 acc[4];
#pragma unroll
    for (int j = 0; j < 4; j++) acc[j] = (f32x4){0.f, 0.f, 0.f, 0.f};
    for (int kt = 0; kt < 8; kt++) {
        int k0 = kt * 32;
        {
            int n = tid >> 2, qc = tid & 3;
            *(int4*)&Bs[n][qc * 8] = *(const int4*)(dWe + (long)n * D_ + k0 + qc * 8);
        }
        __syncthreads();
        bf16x8 af = *(const bf16x8*)&xb[m_local + l15][k0 + kq * 8];
#pragma unroll
        for (int j = 0; j < 4; j++) {
            bf16x8 bf = *(const bf16x8*)&Bs[j * 16 + l15][kq * 8];
            acc[j] = __builtin_amdgcn_mfma_f32_16x16x32_bf16(af, bf, acc[j], 0, 0, 0);
        }
        __syncthreads();
    }
#pragma unroll
    for (int j = 0; j < 4; j++) {
        int col = j * 16 + l15;
        float bv = db[e * RR_ + col];
#pragma unroll
        for (int r = 0; r < 4; r++) {
            long m = row0 + m_local + kq * 4 + r;
            h[m * RR_ + col] = gelu_f(acc[j][r] + bv);
        }
    }
}

// ---------------- K8b: depth-conv, all 3 experts in one launch -> bf16 ----------------
__global__ __launch_bounds__(256) void k_conv_all(
    const float* __restrict__ hall, const float* __restrict__ cw1,
    const float* __restrict__ cw3, const float* __restrict__ cw5,
    const float* __restrict__ conv_b, unsigned short* __restrict__ hcbb)
{
    __shared__ float hs[68][68];
    __shared__ float wt[64][64];
    int e = blockIdx.y;
    const float* w = (e == 0) ? cw1 : ((e == 1) ? cw3 : cw5);
    int ksz = (e == 0) ? 1 : ((e == 1) ? 3 : 5);
    const float* h = hall + (long)e * NRT * RR_;
    unsigned short* hcb = hcbb + (long)e * NRT * RR_;
    const float* cb = conv_b + e * 64;
    int b = blockIdx.x & 15;
    int m0 = (blockIdx.x >> 4) * 64;
    int tid = threadIdx.x;
    int pad = (ksz - 1) >> 1;
    for (int idx = tid; idx < 68 * 16; idx += 256) {
        int mr = idx >> 4, i4 = idx & 15;
        int mm = m0 - 2 + mr;
        float4 vv = { 0.f, 0.f, 0.f, 0.f };
        if (mm >= 0 && mm < LT) vv = *(const float4*)(h + ((long)b * LT + mm) * RR_ + i4 * 4);
        *(float4*)&hs[mr][i4 * 4] = vv;
    }
    int tx = tid & 15, ty = tid >> 4;
    float acc[4][4] = {};
    for (int t = 0; t < ksz; t++) {
        __syncthreads();
        for (int idx = tid; idx < 4096; idx += 256) {
            int i = idx & 63, j = idx >> 6;
            wt[i][j] = w[(long)j * RR_ * ksz + i * ksz + t];
        }
        __syncthreads();
        int roff = ty * 4 + 2 + t - pad;
        for (int i4 = 0; i4 < 16; i4++) {
            float4 h0 = *(const float4*)&hs[roff + 0][i4 * 4];
            float4 h1 = *(const float4*)&hs[roff + 1][i4 * 4];
            float4 h2 = *(const float4*)&hs[roff + 2][i4 * 4];
            float4 h3 = *(const float4*)&hs[roff + 3][i4 * 4];
            float hh[4][4] = { { h0.x, h0.y, h0.z, h0.w }, { h1.x, h1.y, h1.z, h1.w },
                               { h2.x, h2.y, h2.z, h2.w }, { h3.x, h3.y, h3.z, h3.w } };
#pragma unroll
            for (int s = 0; s < 4; s++) {
                float4 wv = *(const float4*)&wt[i4 * 4 + s][tx * 4];
#pragma unroll
                for (int r = 0; r < 4; r++) {
                    acc[r][0] += hh[r][s] * wv.x;
                    acc[r][1] += hh[r][s] * wv.y;
                    acc[r][2] += hh[r][s] * wv.z;
                    acc[r][3] += hh[r][s] * wv.w;
                }
            }
        }
    }
    float4 bb = *(const float4*)(cb + tx * 4);
#pragma unroll
    for (int r = 0; r < 4; r++) {
        long m = (long)b * LT + m0 + ty * 4 + r;
        unsigned long long pv =
              (unsigned long long)cvt_pk_bf16(gelu_f(acc[r][0] + bb.x), gelu_f(acc[r][1] + bb.y))
            | ((unsigned long long)cvt_pk_bf16(gelu_f(acc[r][2] + bb.z), gelu_f(acc[r][3] + bb.w)) << 32);
        *(unsigned long long*)(hcb + m * RR_ + tx * 4) = pv;
    }
}

// ---------------- K8c: all 3 experts: up-proj + resid(bf16) + LN + gated sum ----------------
__global__ __launch_bounds__(256) void k_up3(
    const unsigned short* __restrict__ hcbb, const unsigned short* __restrict__ uWb,
    const float* __restrict__ up_b, const unsigned short* __restrict__ residb,
    const float* __restrict__ en_g, const float* __restrict__ en_b,
    const float* __restrict__ G, float* __restrict__ out)
{
    __shared__ short hs[64][88];
    __shared__ short Bs[256][40];
    int tid = threadIdx.x;
    int b = blockIdx.x & 15;
    int mseg = blockIdx.x >> 4;
    long row0 = (long)b * LT + mseg * 64;
    int wid = tid >> 6, lane = tid & 63;
    int l15 = lane & 15, kq = lane >> 4;
    int m_local = wid * 16;
    long mrow[4];
#pragma unroll
    for (int r = 0; r < 4; r++) mrow[r] = row0 + m_local + kq * 4 + r;
    f32x4 outacc[16];
#pragma unroll
    for (int j = 0; j < 16; j++) outacc[j] = (f32x4){0.f, 0.f, 0.f, 0.f};
    for (int e = 0; e < 3; e++) {
        __syncthreads();   // prior expert's LDS readers done
        const unsigned short* hcb = hcbb + (long)e * NRT * RR_;
        const unsigned short* uWe = uWb + (long)e * 16384;
#pragma unroll
        for (int hh = 0; hh < 2; hh++) {
            int idx = tid + 256 * hh;
            int row = idx >> 3, ch = idx & 7;
            *(int4*)&hs[row][ch * 8] = *(const int4*)(hcb + (row0 + row) * RR_ + ch * 8);
        }
        f32x4 acc[16];
#pragma unroll
        for (int j = 0; j < 16; j++) acc[j] = (f32x4){0.f, 0.f, 0.f, 0.f};
        for (int kt = 0; kt < 2; kt++) {
            int k0 = kt * 32;
#pragma unroll
            for (int hh = 0; hh < 4; hh++) {
                int idx = tid + 256 * hh;
                int n = idx >> 2, qc = idx & 3;
                *(int4*)&Bs[n][qc * 8] = *(const int4*)(uWe + (long)n * RR_ + k0 + qc * 8);
            }
            __syncthreads();
            bf16x8 af = *(const bf16x8*)&hs[m_local + l15][k0 + kq * 8];
#pragma unroll
            for (int j = 0; j < 16; j++) {
                bf16x8 bf = *(const bf16x8*)&Bs[j * 16 + l15][kq * 8];
                acc[j] = __builtin_amdgcn_mfma_f32_16x16x32_bf16(af, bf, acc[j], 0, 0, 0);
            }
            __syncthreads();
        }
        const float* ub = up_b + e * 256;
#pragma unroll
        for (int j = 0; j < 16; j++) {
            int col = j * 16 + l15;
            float bv = ub[col];
#pragma unroll
            for (int r = 0; r < 4; r++)
                acc[j][r] += bv + bf2f(residb[mrow[r] * D_ + col]);
        }
        float s[4] = {0.f, 0.f, 0.f, 0.f};
#pragma unroll
        for (int j = 0; j < 16; j++)
#pragma unroll
            for (int r = 0; r < 4; r++) s[r] += acc[j][r];
#pragma unroll
        for (int off = 8; off >= 1; off >>= 1)
#pragma unroll
            for (int r = 0; r < 4; r++) s[r] += __shfl_xor(s[r], off);
        float mn[4];
#pragma unroll
        for (int r = 0; r < 4; r++) mn[r] = s[r] * (1.0f / 256.0f);
        float q[4] = {0.f, 0.f, 0.f, 0.f};
#pragma unroll
        for (int j = 0; j < 16; j++)
#pragma unroll
            for (int r = 0; r < 4; r++) { float d = acc[j][r] - mn[r]; q[r] += d * d; }
#pragma unroll
        for (int off = 8; off >= 1; off >>= 1)
#pragma unroll
            for (int r = 0; r < 4; r++) q[r] += __shfl_xor(q[r], off);
        float iv[4], gv[4];
#pragma unroll
        for (int r = 0; r < 4; r++) {
            iv[r] = rsqrtf(q[r] * (1.0f / 256.0f) + 1e-5f);
            gv[r] = G[(long)e * NRT + mrow[r]];
        }
        const float* eg = en_g + e * 256;
        const float* eb = en_b + e * 256;
#pragma unroll
        for (int j = 0; j < 16; j++) {
            int col = j * 16 + l15;
            float egc = eg[col], ebc = eb[col];
#pragma unroll
            for (int r = 0; r < 4; r++)
                outacc[j][r] += gv[r] * ((acc[j][r] - mn[r]) * iv[r] * egc + ebc);
        }
    }
#pragma unroll
    for (int j = 0; j < 16; j++) {
        int col = j * 16 + l15;
#pragma unroll
        for (int r = 0; r < 4; r++)
            out[mrow[r] * D_ + col] = outacc[j][r];
    }
}

extern "C" void kernel_launch(void* const* d_in, const int* in_sizes, int n_in,
                              void* d_out, int out_size, void* d_ws, size_t ws_size,
                              hipStream_t stream)
{
    const float* text   = (const float*)d_in[0];
    const float* audio  = (const float*)d_in[1];
    const float* ln_g   = (const float*)d_in[2];
    const float* ln_b   = (const float*)d_in[3];
    const float* W_sh   = (const float*)d_in[4];
    const float* b_sh   = (const float*)d_in[5];
    const float* Wr1    = (const float*)d_in[6];
    const float* br1    = (const float*)d_in[7];
    const float* Wr2    = (const float*)d_in[8];
    const float* br2    = (const float*)d_in[9];
    const float* down_W = (const float*)d_in[10];
    const float* down_b = (const float*)d_in[11];
    const float* cw1    = (const float*)d_in[12];
    const float* cw3    = (const float*)d_in[13];
    const float* cw5    = (const float*)d_in[14];
    const float* conv_b = (const float*)d_in[15];
    const float* up_W   = (const float*)d_in[16];
    const float* up_b   = (const float*)d_in[17];
    const float* en_g   = (const float*)d_in[18];
    const float* en_b   = (const float*)d_in[19];

    float* ws = (float*)d_ws;
    float*          Tp    = ws;                               // 4,194,304 f
    unsigned short* Tnb   = (unsigned short*)(ws + 4194304);  // 2,097,152 f
    unsigned short* Anb   = (unsigned short*)(ws + 6291456);  // 4,194,304 f
    unsigned short* ApbT  = (unsigned short*)(ws + 10485760); // 4,194,304 f  (plain Ap^T bf16)
    unsigned char*  logK8 = (unsigned char*)(ws + 14680064);  // 8,388,608 f (33.5 MB u8)
    unsigned short* Apart = (unsigned short*)(ws + 23068672); // 2 x bf16 halves (16 MB of region)
    unsigned short* residb= (unsigned short*)(ws + 35651584); // 2,097,152 f
    float*          lu2   = ws + 37748736;                    // 16,384  (log2-domain)
    float*          lv2   = ws + 37765120;                    // 32,768  (log2-domain)
    float*          Sb    = ws + 37797888;                    // 16,384
    float*          Gb    = ws + 37814272;                    // 49,152
    unsigned short* Wb    = (unsigned short*)(ws + 37863424); // 32,768 f
    unsigned short* dWb   = (unsigned short*)(ws + 37896192); // 24,576 f
    unsigned short* uWb   = (unsigned short*)(ws + 37920768); // 24,576 f
    unsigned short* Wr1b  = (unsigned short*)(ws + 37945344); // 32,768 f
    size_t need_bytes = (size_t)37978112 * 4;
    if (ws_size < need_bytes) {
        fprintf(stderr, "kernel_launch: ws_size %zu < needed %zu\n", ws_size, need_bytes);
        return;
    }
    // aliases in logK8 region (dead after k_pi2):
    float*          hall = ws + 14680064;                     // 3,145,728 f
    unsigned short* hcbb = (unsigned short*)(ws + 17825792);  // 1,572,864 f
    // logK8T aliases the Apart region (33,554,432 B): written by k_cost_mfma, read by
    // k_collse4 x10, dead before k_pi2 writes Apart (stream-ordered).
    unsigned char*  logK8T = (unsigned char*)(ws + 23068672);

    k_prep_all<<<896, 256, 0, stream>>>(W_sh, down_W, up_W, Wr1, Wb, dWb, uWb, Wr1b);
    k_lnproj_fused<<<(NRT + NRA) / 64, 256, 0, stream>>>(text, audio, ln_g, ln_b, Wb, b_sh,
                                                         Tp, Tnb, Anb, ApbT);
    k_cost_mfma<<<dim3(NB, LT / 128, LA / 128), 256, 0, stream>>>(Tnb, Anb, logK8, logK8T);
    for (int it = 0; it < 10; it++) {
        k_rowlse4<<<NRT / 8, 256, 0, stream>>>(logK8, lv2, lu2, it == 0 ? 1 : 0);
        k_collse4<<<NB * (LA / 16), 256, 0, stream>>>(logK8T, lu2, lv2);
    }
    k_pi2<<<dim3(NB, 2, LT / 64), 256, 0, stream>>>(logK8, ApbT, lu2, lv2, Apart);
    k_sresid<<<NRT, 256, 0, stream>>>(Tp, Apart, residb, Sb);
    k_router_fused<<<NRT / 16, 256, 0, stream>>>(residb, Wr1b, Wr1, br1, Sb, Wr2, br2, Gb);
    k_down_mfma<<<dim3(NRT / 64, 3), 256, 0, stream>>>(residb, dWb, down_b, hall);
    k_conv_all<<<dim3(NRT / 64, 3), 256, 0, stream>>>(hall, cw1, cw3, cw5, conv_b, hcbb);
    k_up3<<<NRT / 64, 256, 0, stream>>>(hcbb, uWb, up_b, residb, en_g, en_b, Gb, (float*)d_out);
}

// Round 13
// 494.318 us; speedup vs baseline: 1.0691x; 1.0691x over previous
//
#include <hip/hip_runtime.h>
#include <cstdio>

#define D_ 256
#define LT 1024
#define LA 2048
#define NB 16
#define RR_ 64
#define NRT (NB*LT)   // 16384 text rows
#define NRA (NB*LA)   // 32768 audio rows

// logK u8 quantization: q = rint((1-cos)*124), logK_hat = q * DECQ (nat log)
// exp2 domain: DECQ2 = DECQ * log2(e)
#define DECQ  (-0.080645161f)
#define DECQ2 (-0.11634637f)

typedef short bf16x8 __attribute__((ext_vector_type(8)));
typedef float f32x4 __attribute__((ext_vector_type(4)));

__device__ __forceinline__ float gelu_f(float x) {
    return 0.5f * x * (1.0f + erff(x * 0.70710678118654752f));
}
__device__ __forceinline__ unsigned short f2bf(float f) {   // RNE
    union { float f; unsigned int i; } c; c.f = f;
    unsigned int x = c.i;
    return (unsigned short)((x + 0x7fffu + ((x >> 16) & 1u)) >> 16);
}
__device__ __forceinline__ float bf2f(unsigned short u) {
    return __uint_as_float((unsigned int)u << 16);
}
// raw v_exp_f32: args here are always > -126, so no denormal fixup needed
__device__ __forceinline__ float exp2_fast(float x) {
#if __has_builtin(__builtin_amdgcn_exp2f)
    return __builtin_amdgcn_exp2f(x);
#else
    float r; asm("v_exp_f32 %0, %1" : "=v"(r) : "v"(x)); return r;
#endif
}
// pack 2 f32 -> 2 bf16 (RNE) in one instruction; lo = first arg
__device__ __forceinline__ unsigned int cvt_pk_bf16(float lo, float hi) {
    unsigned int r;
    asm("v_cvt_pk_bf16_f32 %0, %1, %2" : "=v"(r) : "v"(lo), "v"(hi));
    return r;
}

// ---------------- prep: all weight fp32->bf16 conversions in ONE launch ----------------
__global__ __launch_bounds__(256) void k_prep_all(
    const float* __restrict__ W_sh, const float* __restrict__ down_W,
    const float* __restrict__ up_W, const float* __restrict__ Wr1,
    unsigned short* __restrict__ Wb, unsigned short* __restrict__ dWb,
    unsigned short* __restrict__ uWb, unsigned short* __restrict__ Wr1b)
{
    int i = blockIdx.x * 256 + threadIdx.x;          // 0 .. 229375
    if (i < 65536) Wb[i] = f2bf(W_sh[i]);
    else if (i < 114688) { int j = i - 65536; dWb[j] = f2bf(down_W[j]); }
    else if (i < 163840) { int j = i - 114688; uWb[j] = f2bf(up_W[j]); }
    else { int j = i - 163840; int n = j >> 8, k = j & 255; Wr1b[j] = f2bf(Wr1[(long)n * 257 + 1 + k]); }
}

// ---------------- K1: LayerNorm + shared projection (MFMA), text+audio fused ----------------
// blocks [0, 256): text rows -> Tp + Tnb.  blocks [256, 768): audio rows -> Anb + ApbT.
// W staged through LDS in TWO N-halves (Bs [128][40]) -> LDS 44032 B -> 3 blocks/CU.
__global__ __launch_bounds__(256) void k_lnproj_fused(
    const float* __restrict__ Xt, const float* __restrict__ Xa,
    const float* __restrict__ g, const float* __restrict__ bln,
    const unsigned short* __restrict__ Wb, const float* __restrict__ bsh,
    float* __restrict__ Tp, unsigned short* __restrict__ Tnb,
    unsigned short* __restrict__ Anb, unsigned short* __restrict__ ApbT)
{
    __shared__ short smem[64 * 264 + 128 * 40];          // 44032 B -> 3 blocks/CU
    short (*xb)[264] = (short(*)[264])smem;
    short (*Bs)[40]  = (short(*)[40])(smem + 64 * 264);
    short (*tt)[72]  = (short(*)[72])smem;               // 36864 B, aliases xb+Bs (dead post-loop)
    int tid = threadIdx.x;
    int bid = blockIdx.x;
    bool is_text = bid < (NRT / 64);
    const float* X = is_text ? Xt : Xa;
    long row0 = is_text ? (long)bid * 64 : (long)(bid - NRT / 64) * 64;
    {
        int lane = tid & 31, rg = tid >> 5;
        float4 ga = *(const float4*)(g + lane * 8);
        float4 gb2 = *(const float4*)(g + lane * 8 + 4);
        float4 ba = *(const float4*)(bln + lane * 8);
        float4 bb2 = *(const float4*)(bln + lane * 8 + 4);
        for (int it = 0; it < 8; it++) {
            int r = it * 8 + rg;
            const float4* xp4 = (const float4*)(X + (row0 + r) * D_);
            float4 a = xp4[lane * 2], b = xp4[lane * 2 + 1];
            float s = a.x + a.y + a.z + a.w + b.x + b.y + b.z + b.w;
#pragma unroll
            for (int off = 16; off >= 1; off >>= 1) s += __shfl_xor(s, off);
            float mean = s * (1.0f / 256.0f);
            float q = (a.x - mean) * (a.x - mean) + (a.y - mean) * (a.y - mean)
                    + (a.z - mean) * (a.z - mean) + (a.w - mean) * (a.w - mean)
                    + (b.x - mean) * (b.x - mean) + (b.y - mean) * (b.y - mean)
                    + (b.z - mean) * (b.z - mean) + (b.w - mean) * (b.w - mean);
#pragma unroll
            for (int off = 16; off >= 1; off >>= 1) q += __shfl_xor(q, off);
            float ivar = rsqrtf(q * (1.0f / 256.0f) + 1e-5f);
            float v0 = (a.x - mean) * ivar * ga.x + ba.x;
            float v1 = (a.y - mean) * ivar * ga.y + ba.y;
            float v2 = (a.z - mean) * ivar * ga.z + ba.z;
            float v3 = (a.w - mean) * ivar * ga.w + ba.w;
            float v4 = (b.x - mean) * ivar * gb2.x + bb2.x;
            float v5 = (b.y - mean) * ivar * gb2.y + bb2.y;
            float v6 = (b.z - mean) * ivar * gb2.z + bb2.z;
            float v7 = (b.w - mean) * ivar * gb2.w + bb2.w;
            int4 pv;
            pv.x = (int)cvt_pk_bf16(v0, v1); pv.y = (int)cvt_pk_bf16(v2, v3);
            pv.z = (int)cvt_pk_bf16(v4, v5); pv.w = (int)cvt_pk_bf16(v6, v7);
            *(int4*)&xb[r][lane * 8] = pv;
        }
    }
    __syncthreads();
    int wid = tid >> 6, lane = tid & 63;
    int l15 = lane & 15, kq = lane >> 4;
    int m_local = wid * 16;
    f32x4 acc[16];
#pragma unroll
    for (int j = 0; j < 16; j++) acc[j] = (f32x4){0.f, 0.f, 0.f, 0.f};
    for (int kt = 0; kt < 8; kt++) {
        int k0 = kt * 32;
        bf16x8 af = *(const bf16x8*)&xb[m_local + l15][k0 + kq * 8];
        // half 0: W rows 0..127
#pragma unroll
        for (int h = 0; h < 2; h++) {
            int idx = tid + 256 * h;
            int n = idx >> 2, qc = idx & 3;
            *(int4*)&Bs[n][qc * 8] = *(const int4*)(Wb + (long)n * D_ + k0 + qc * 8);
        }
        __syncthreads();
#pragma unroll
        for (int j = 0; j < 8; j++) {
            bf16x8 bf = *(const bf16x8*)&Bs[j * 16 + l15][kq * 8];
            acc[j] = __builtin_amdgcn_mfma_f32_16x16x32_bf16(af, bf, acc[j], 0, 0, 0);
        }
        __syncthreads();
        // half 1: W rows 128..255
#pragma unroll
        for (int h = 0; h < 2; h++) {
            int idx = tid + 256 * h;
            int n = idx >> 2, qc = idx & 3;
            *(int4*)&Bs[n][qc * 8] = *(const int4*)(Wb + (long)(128 + n) * D_ + k0 + qc * 8);
        }
        __syncthreads();
#pragma unroll
        for (int j = 0; j < 8; j++) {
            bf16x8 bf = *(const bf16x8*)&Bs[j * 16 + l15][kq * 8];
            acc[8 + j] = __builtin_amdgcn_mfma_f32_16x16x32_bf16(af, bf, acc[8 + j], 0, 0, 0);
        }
        __syncthreads();
    }
#pragma unroll
    for (int j = 0; j < 16; j++) {
        float bv = bsh[j * 16 + l15];
#pragma unroll
        for (int r = 0; r < 4; r++) acc[j][r] += bv;
    }
    float sq[4] = {0.f, 0.f, 0.f, 0.f};
#pragma unroll
    for (int j = 0; j < 16; j++)
#pragma unroll
        for (int r = 0; r < 4; r++) sq[r] += acc[j][r] * acc[j][r];
#pragma unroll
    for (int off = 8; off >= 1; off >>= 1) {
#pragma unroll
        for (int r = 0; r < 4; r++) sq[r] += __shfl_xor(sq[r], off);
    }
    float rinv[4];
#pragma unroll
    for (int r = 0; r < 4; r++) rinv[r] = 1.0f / fmaxf(sqrtf(sq[r]), 1e-12f);
    if (is_text) {
#pragma unroll
        for (int j = 0; j < 16; j++) {
            int col = j * 16 + l15;
#pragma unroll
            for (int r = 0; r < 4; r++) {
                long m = row0 + m_local + kq * 4 + r;
                Tp[m * D_ + col] = acc[j][r];
                Tnb[m * D_ + col] = f2bf(acc[j][r] * rinv[r]);
            }
        }
    } else {
        // write Anb row-major + stage normalized tile into LDS for ApbT transpose.
        // tt aliases xb/Bs: both are dead after the K-loop's final __syncthreads.
#pragma unroll
        for (int j = 0; j < 16; j++) {
            int col = j * 16 + l15;
#pragma unroll
            for (int r = 0; r < 4; r++) {
                int rloc = m_local + kq * 4 + r;
                unsigned short qv = f2bf(acc[j][r] * rinv[r]);
                Anb[(row0 + rloc) * D_ + col] = qv;
                tt[col][rloc] = (short)qv;
            }
        }
        __syncthreads();
        int b = (int)(row0 >> 11);           // LA = 2048
        int n0 = (int)(row0 & 2047);
#pragma unroll
        for (int h = 0; h < 8; h++) {
            int ci = tid + 256 * h;          // 2048 int4 chunks
            int col = ci >> 3, nch = ci & 7;
            int4 v = *(const int4*)&tt[col][nch * 8];
            *(int4*)(ApbT + ((long)b * D_ + col) * LA + n0 + nch * 8) = v;
        }
    }
}

// ---------------- K2: cost GEMM (MFMA bf16) -> logK u8 + transposed logK8T ----------------
__global__ __launch_bounds__(256) void k_cost_mfma(
    const unsigned short* __restrict__ Tnb, const unsigned short* __restrict__ Anb,
    unsigned char* __restrict__ logK8, unsigned char* __restrict__ logK8T)
{
    __shared__ short sm[2][128][48];
    short (*As)[48] = sm[0];
    short (*Bs)[48] = sm[1];
    unsigned char* tile = (unsigned char*)sm;
    int b = blockIdx.x;
    int m_blk = blockIdx.y * 128, n_blk = blockIdx.z * 128;
    int tid = threadIdx.x;
    int wid = tid >> 6, lane = tid & 63;
    int l15 = lane & 15, kq = lane >> 4;
    int wm0 = (wid >> 1) * 64, wn0 = (wid & 1) * 64;
    const unsigned short* Ab = Tnb + ((long)b * LT + m_blk) * D_;
    const unsigned short* Bb = Anb + ((long)b * LA + n_blk) * D_;
    f32x4 acc[4][4];
#pragma unroll
    for (int i = 0; i < 4; i++)
#pragma unroll
        for (int j = 0; j < 4; j++) acc[i][j] = (f32x4){0.f, 0.f, 0.f, 0.f};
    for (int kt = 0; kt < 8; kt++) {
        int k0 = kt * 32;
#pragma unroll
        for (int h = 0; h < 2; h++) {
            int idx = tid + 256 * h;
            int row = idx >> 2, ch = idx & 3;
            *(int4*)&As[row][ch * 8] = *(const int4*)(Ab + (long)row * D_ + k0 + ch * 8);
            *(int4*)&Bs[row][ch * 8] = *(const int4*)(Bb + (long)row * D_ + k0 + ch * 8);
        }
        __syncthreads();
        bf16x8 af[4], bfv[4];
#pragma unroll
        for (int i = 0; i < 4; i++) af[i] = *(const bf16x8*)&As[wm0 + i * 16 + l15][kq * 8];
#pragma unroll
        for (int j = 0; j < 4; j++) bfv[j] = *(const bf16x8*)&Bs[wn0 + j * 16 + l15][kq * 8];
#pragma unroll
        for (int i = 0; i < 4; i++)
#pragma unroll
            for (int j = 0; j < 4; j++)
                acc[i][j] = __builtin_amdgcn_mfma_f32_16x16x32_bf16(af[i], bfv[j], acc[i][j], 0, 0, 0);
        __syncthreads();
    }
    // quantize once: direct row-major byte stores + packed u32 into transpose tile
#pragma unroll
    for (int i = 0; i < 4; i++) {
#pragma unroll
        for (int j = 0; j < 4; j++) {
            int n = wn0 + j * 16 + l15;                       // n_local
            long base = ((long)b * LT + m_blk + wm0 + i * 16 + kq * 4) * (long)LA + n_blk + n;
            unsigned int pk = 0;
#pragma unroll
            for (int r = 0; r < 4; r++) {
                float q = rintf((1.0f - acc[i][j][r]) * 124.0f);
                q = fminf(fmaxf(q, 0.0f), 255.0f);
                unsigned int qb = (unsigned int)q;
                pk |= qb << (8 * r);
                logK8[base + (long)r * LA] = (unsigned char)qb;
            }
            *(unsigned int*)&tile[n * 144 + wm0 + i * 16 + kq * 4] = pk;
        }
    }
    __syncthreads();
#pragma unroll
    for (int h = 0; h < 4; h++) {
        int idx = tid + 256 * h;
        int row = idx >> 3, ch = idx & 7;                    // 128 n-rows x 8 int4 chunks
        int4 v = *(const int4*)&tile[row * 144 + ch * 16];
        *(int4*)(logK8T + ((long)b * LA + n_blk + row) * (long)LT + m_blk + ch * 16) = v;
    }
}

// ---------------- K3: row LSE, 8 rows/block, lv slice in regs reused 4x ----------------
__global__ __launch_bounds__(256) void k_rowlse4(
    const unsigned char* __restrict__ logK8, const float* __restrict__ lv2,
    float* __restrict__ lu2, int first)
{
    __shared__ float red[8][2];
    int b = blockIdx.x & 15;
    int mseg = blockIdx.x >> 4;          // 0..127, 8 rows each
    int tid = threadIdx.x;
    int rg = tid >> 7;                   // 0..1 row group
    int ln = tid & 127;                  // lane within row (x16 bytes)
    float lvv[16];
    if (!first) {
        const float* lvp = lv2 + (long)b * LA + ln * 16;
#pragma unroll
        for (int k = 0; k < 4; k++) {
            float4 l = *(const float4*)(lvp + k * 4);
            lvv[k * 4 + 0] = l.x; lvv[k * 4 + 1] = l.y;
            lvv[k * 4 + 2] = l.z; lvv[k * 4 + 3] = l.w;
        }
    } else {
#pragma unroll
        for (int k = 0; k < 16; k++) lvv[k] = 0.f;
    }
    const unsigned char* p = logK8 + ((long)b * LT + mseg * 8 + rg * 4) * (long)LA + ln * 16;
#pragma unroll
    for (int r = 0; r < 4; r++) {
        uint4 w = *(const uint4*)(p + (long)r * LA);
        unsigned int ws4[4] = {w.x, w.y, w.z, w.w};
        float s = 0.f;
#pragma unroll
        for (int k = 0; k < 4; k++) {
            unsigned int u = ws4[k];
            s += exp2_fast(fmaf((float)(u & 0xffu),         DECQ2, lvv[k * 4 + 0]));
            s += exp2_fast(fmaf((float)((u >> 8) & 0xffu),  DECQ2, lvv[k * 4 + 1]));
            s += exp2_fast(fmaf((float)((u >> 16) & 0xffu), DECQ2, lvv[k * 4 + 2]));
            s += exp2_fast(fmaf((float)(u >> 24),           DECQ2, lvv[k * 4 + 3]));
        }
#pragma unroll
        for (int off = 32; off >= 1; off >>= 1) s += __shfl_xor(s, off);
        if ((tid & 63) == 0) red[rg * 4 + r][(tid >> 6) & 1] = s;
    }
    __syncthreads();
    if (tid < 8) {
        float sr = red[tid][0] + red[tid][1];
        lu2[(long)b * LT + mseg * 8 + tid] = -10.0f - __log2f(sr);   // -log2(Lt) - log2(s)
    }
}

// ---------------- K4: col LSE over logK8T, 16 cols/block, lu slice in regs reused 4x ----------
__global__ __launch_bounds__(256) void k_collse4(
    const unsigned char* __restrict__ logK8T, const float* __restrict__ lu2,
    float* __restrict__ lv2)
{
    int b = blockIdx.x & 15;
    int nseg = blockIdx.x >> 4;          // 0..127, 16 cols each
    int tid = threadIdx.x;
    int wv = tid >> 6, lane = tid & 63;
    float lus[16];
    const float* lup = lu2 + (long)b * LT + lane * 16;
#pragma unroll
    for (int k = 0; k < 4; k++) {
        float4 l = *(const float4*)(lup + k * 4);
        lus[k * 4 + 0] = l.x; lus[k * 4 + 1] = l.y;
        lus[k * 4 + 2] = l.z; lus[k * 4 + 3] = l.w;
    }
    const unsigned char* p = logK8T + ((long)b * LA + nseg * 16 + wv * 4) * (long)LT + lane * 16;
#pragma unroll
    for (int cs = 0; cs < 4; cs++) {
        uint4 w = *(const uint4*)(p + (long)cs * LT);
        unsigned int ws4[4] = {w.x, w.y, w.z, w.w};
        float s = 0.f;
#pragma unroll
        for (int k = 0; k < 4; k++) {
            unsigned int u = ws4[k];
            s += exp2_fast(fmaf((float)(u & 0xffu),         DECQ2, lus[k * 4 + 0]));
            s += exp2_fast(fmaf((float)((u >> 8) & 0xffu),  DECQ2, lus[k * 4 + 1]));
            s += exp2_fast(fmaf((float)((u >> 16) & 0xffu), DECQ2, lus[k * 4 + 2]));
            s += exp2_fast(fmaf((float)(u >> 24),           DECQ2, lus[k * 4 + 3]));
        }
#pragma unroll
        for (int off = 32; off >= 1; off >>= 1) s += __shfl_xor(s, off);
        if (lane == 0)
            lv2[(long)b * LA + nseg * 16 + wv * 4 + cs] = -11.0f - __log2f(s);
    }
}

// ---------------- K5: A_al = eu * ((F*ev) @ Ap); bf16 output, K-split x2 (r10 proven) --------
__global__ __launch_bounds__(256) void k_pi2(
    const unsigned char* __restrict__ logK8, const unsigned short* __restrict__ Ap,
    const float* __restrict__ lu2, const float* __restrict__ lv2,
    unsigned short* __restrict__ Apart)
{
    __shared__ short As[64][56];       // stride 112B = 28 dw: rows r,r+8 alias -> free 2-way only
    __shared__ short Bs[256][56];
    __shared__ float lv_s[1024];
    __shared__ float eus[64];
    int b = blockIdx.x;
    int kh = blockIdx.y;               // 0..1: half of the n axis
    int m_blk = blockIdx.z * 64;
    int nbase = kh * 1024;
    int tid = threadIdx.x;
    for (int i = tid; i < 1024; i += 256) lv_s[i] = lv2[(long)b * LA + nbase + i];
    if (tid < 64) eus[tid] = exp2_fast(lu2[(long)b * LT + m_blk + tid]);
    __syncthreads();
    int wid = tid >> 6, lane = tid & 63;
    int l15 = lane & 15, kq = lane >> 4;
    int wm0 = (wid & 1) * 32, wd0 = (wid >> 1) * 128;
    f32x4 acc[2][8];
#pragma unroll
    for (int i = 0; i < 2; i++)
#pragma unroll
        for (int j = 0; j < 8; j++) acc[i][j] = (f32x4){0.f, 0.f, 0.f, 0.f};
    const unsigned char* Kbase = logK8 + ((long)b * LT + m_blk) * (long)LA + nbase;
    const unsigned short* Bbase = Ap + (long)b * D_ * (long)LA + nbase;
    int arow = tid >> 2, ac8 = (tid & 3) * 8;
    for (int kt = 0; kt < 32; kt++) {
        int n0 = kt * 32;
        {
            uint2 raw = *(const uint2*)(Kbase + (long)arow * LA + n0 + ac8);
            const float* lvp = &lv_s[n0 + ac8];
            unsigned int w0 = raw.x, w1 = raw.y;
            float e0 = exp2_fast(fmaf((float)(w0 & 0xffu),         DECQ2, lvp[0]));
            float e1 = exp2_fast(fmaf((float)((w0 >> 8) & 0xffu),  DECQ2, lvp[1]));
            float e2 = exp2_fast(fmaf((float)((w0 >> 16) & 0xffu), DECQ2, lvp[2]));
            float e3 = exp2_fast(fmaf((float)(w0 >> 24),           DECQ2, lvp[3]));
            float e4 = exp2_fast(fmaf((float)(w1 & 0xffu),         DECQ2, lvp[4]));
            float e5 = exp2_fast(fmaf((float)((w1 >> 8) & 0xffu),  DECQ2, lvp[5]));
            float e6 = exp2_fast(fmaf((float)((w1 >> 16) & 0xffu), DECQ2, lvp[6]));
            float e7 = exp2_fast(fmaf((float)(w1 >> 24),           DECQ2, lvp[7]));
            int4 ov;
            ov.x = (int)cvt_pk_bf16(e0, e1); ov.y = (int)cvt_pk_bf16(e2, e3);
            ov.z = (int)cvt_pk_bf16(e4, e5); ov.w = (int)cvt_pk_bf16(e6, e7);
            *(int4*)&As[arow][ac8] = ov;
        }
#pragma unroll
        for (int h = 0; h < 4; h++) {
            int idx = tid + 256 * h;
            int row = idx >> 2, ch = idx & 3;
            *(int4*)&Bs[row][ch * 8] = *(const int4*)(Bbase + (long)row * LA + n0 + ch * 8);
        }
        __syncthreads();
        bf16x8 af[2], bfv[8];
        af[0] = *(const bf16x8*)&As[wm0 + l15][kq * 8];
        af[1] = *(const bf16x8*)&As[wm0 + 16 + l15][kq * 8];
#pragma unroll
        for (int j = 0; j < 8; j++) bfv[j] = *(const bf16x8*)&Bs[wd0 + j * 16 + l15][kq * 8];
#pragma unroll
        for (int i = 0; i < 2; i++)
#pragma unroll
            for (int j = 0; j < 8; j++)
                acc[i][j] = __builtin_amdgcn_mfma_f32_16x16x32_bf16(af[i], bfv[j], acc[i][j], 0, 0, 0);
        __syncthreads();
    }
    unsigned short* dst = Apart + (long)kh * (NB * (long)LT * D_);
#pragma unroll
    for (int i = 0; i < 2; i++) {
#pragma unroll
        for (int r = 0; r < 4; r++) {
            int rloc = wm0 + i * 16 + kq * 4 + r;
            float eu = eus[rloc];
            int m = m_blk + rloc;
            long obase = ((long)b * LT + m) * D_;
#pragma unroll
            for (int j = 0; j < 8; j++)
                dst[obase + wd0 + j * 16 + l15] = f2bf(acc[i][j][r] * eu);
        }
    }
}

// ---------------- K6: combine 2 bf16 K-halves, S, residb (batch-fastest) ----------------
__global__ __launch_bounds__(256) void k_sresid(
    const float* __restrict__ Tp, const unsigned short* __restrict__ Apart,
    unsigned short* __restrict__ residb, float* __restrict__ S)
{
    __shared__ float red[4];
    int b = blockIdx.x & 15;
    int m = blockIdx.x >> 4;
    long row = (long)b * LT + m;
    int tid = threadIdx.x;
    long idx = row * D_ + tid;
    float t = Tp[idx];
    float a = bf2f(Apart[idx]) + bf2f(Apart[idx + 1L * NB * LT * D_]);
    float rr = fabsf(t - a);
    residb[idx] = f2bf(rr);
    float p = t * a;
#pragma unroll
    for (int off = 32; off >= 1; off >>= 1) p += __shfl_xor(p, off);
    if ((tid & 63) == 0) red[tid >> 6] = p;
    __syncthreads();
    if (tid == 0) S[row] = red[0] + red[1] + red[2] + red[3];
}

// ---------------- K7: router fused, col-split waves: 16 rows/block ----------------
__global__ __launch_bounds__(256) void k_router_fused(
    const unsigned short* __restrict__ residb, const unsigned short* __restrict__ Wr1b,
    const float* __restrict__ Wr1, const float* __restrict__ br1,
    const float* __restrict__ S, const float* __restrict__ Wr2,
    const float* __restrict__ br2, float* __restrict__ G)
{
    __shared__ short xb[16][264];
    __shared__ short Bs[256][40];
    __shared__ float red[4][3][16];
    int tid = threadIdx.x;
    long row0 = (long)blockIdx.x * 16;
#pragma unroll
    for (int h = 0; h < 2; h++) {
        int idx = tid + 256 * h;
        int row = idx >> 5, ch = idx & 31;
        *(int4*)&xb[row][ch * 8] = *(const int4*)(residb + (row0 + row) * D_ + ch * 8);
    }
    __syncthreads();
    int wid = tid >> 6, lane = tid & 63;
    int l15 = lane & 15, kq = lane >> 4;
    f32x4 acc[4];
#pragma unroll
    for (int j = 0; j < 4; j++) acc[j] = (f32x4){0.f, 0.f, 0.f, 0.f};
    for (int kt = 0; kt < 8; kt++) {
        int k0 = kt * 32;
#pragma unroll
        for (int h = 0; h < 4; h++) {
            int idx = tid + 256 * h;
            int n = idx >> 2, qc = idx & 3;
            *(int4*)&Bs[n][qc * 8] = *(const int4*)(Wr1b + (long)n * D_ + k0 + qc * 8);
        }
        __syncthreads();
        bf16x8 af = *(const bf16x8*)&xb[l15][k0 + kq * 8];
#pragma unroll
        for (int j = 0; j < 4; j++) {
            bf16x8 bf = *(const bf16x8*)&Bs[wid * 64 + j * 16 + l15][kq * 8];
            acc[j] = __builtin_amdgcn_mfma_f32_16x16x32_bf16(af, bf, acc[j], 0, 0, 0);
        }
        __syncthreads();
    }
    float sv[4];
#pragma unroll
    for (int r = 0; r < 4; r++) sv[r] = S[row0 + kq * 4 + r];
    float le[3][4] = {};
#pragma unroll
    for (int j = 0; j < 4; j++) {
        int col = wid * 64 + j * 16 + l15;
        float w0 = Wr1[(long)col * 257];
        float bv = br1[col];
        float w2a = Wr2[col], w2b = Wr2[256 + col], w2c = Wr2[512 + col];
#pragma unroll
        for (int r = 0; r < 4; r++) {
            float hv = gelu_f(acc[j][r] + sv[r] * w0 + bv);
            le[0][r] += hv * w2a;
            le[1][r] += hv * w2b;
            le[2][r] += hv * w2c;
        }
    }
#pragma unroll
    for (int off = 8; off >= 1; off >>= 1)
#pragma unroll
        for (int e = 0; e < 3; e++)
#pragma unroll
            for (int r = 0; r < 4; r++) le[e][r] += __shfl_xor(le[e][r], off);
    if (l15 == 0) {
#pragma unroll
        for (int e = 0; e < 3; e++)
#pragma unroll
            for (int r = 0; r < 4; r++) red[wid][e][kq * 4 + r] = le[e][r];
    }
    __syncthreads();
    if (tid < 16) {
        float L0 = red[0][0][tid] + red[1][0][tid] + red[2][0][tid] + red[3][0][tid] + br2[0];
        float L1 = red[0][1][tid] + red[1][1][tid] + red[2][1][tid] + red[3][1][tid] + br2[1];
        float L2 = red[0][2][tid] + red[1][2][tid] + red[2][2][tid] + red[3][2][tid] + br2[2];
        float mx = fmaxf(L0, fmaxf(L1, L2));
        float e0 = __expf(L0 - mx), e1 = __expf(L1 - mx), e2 = __expf(L2 - mx);
        float inv = 1.0f / (e0 + e1 + e2);
        long m = row0 + tid;
        G[m] = e0 * inv; G[NRT + m] = e1 * inv; G[2 * NRT + m] = e2 * inv;
    }
}

// ---------------- K8a: h[e] = gelu(residb @ down_W[e]^T + down_b[e]) ----------------
__global__ __launch_bounds__(256) void k_down_mfma(
    const unsigned short* __restrict__ residb, const unsigned short* __restrict__ dWb,
    const float* __restrict__ db, float* __restrict__ hall)
{
    __shared__ short xb[64][264];
    __shared__ short Bs[64][40];
    int tid = threadIdx.x;
    int e = blockIdx.y;
    int b = blockIdx.x & 15;
    int mseg = blockIdx.x >> 4;
    long row0 = (long)b * LT + mseg * 64;
    const unsigned short* dWe = dWb + (long)e * RR_ * D_;
    float* h = hall + (long)e * NRT * RR_;
#pragma unroll
    for (int hh = 0; hh < 8; hh++) {
        int idx = tid + 256 * hh;
        int row = idx >> 5, ch = idx & 31;
        *(int4*)&xb[row][ch * 8] = *(const int4*)(residb + (row0 + row) * D_ + ch * 8);
    }
    __syncthreads();
    int wid = tid >> 6, lane = tid & 63;
    int l15 = lane & 15, kq = lane >> 4;
    int m_local = wid * 16;
    f32x4 acc[4];
#pragma unroll
    for (int j = 0; j < 4; j++) acc[j] = (f32x4){0.f, 0.f, 0.f, 0.f};
    for (int kt = 0; kt < 8; kt++) {
        int k0 = kt * 32;
        {
            int n = tid >> 2, qc = tid & 3;
            *(int4*)&Bs[n][qc * 8] = *(const int4*)(dWe + (long)n * D_ + k0 + qc * 8);
        }
        __syncthreads();
        bf16x8 af = *(const bf16x8*)&xb[m_local + l15][k0 + kq * 8];
#pragma unroll
        for (int j = 0; j < 4; j++) {
            bf16x8 bf = *(const bf16x8*)&Bs[j * 16 + l15][kq * 8];
            acc[j] = __builtin_amdgcn_mfma_f32_16x16x32_bf16(af, bf, acc[j], 0, 0, 0);
        }
        __syncthreads();
    }
#pragma unroll
    for (int j = 0; j < 4; j++) {
        int col = j * 16 + l15;
        float bv = db[e * RR_ + col];
#pragma unroll
        for (int r = 0; r < 4; r++) {
            long m = row0 + m_local + kq * 4 + r;
            h[m * RR_ + col] = gelu_f(acc[j][r] + bv);
        }
    }
}

// ---------------- K8b: depth-conv, all 3 experts in one launch -> bf16 ----------------
__global__ __launch_bounds__(256) void k_conv_all(
    const float* __restrict__ hall, const float* __restrict__ cw1,
    const float* __restrict__ cw3, const float* __restrict__ cw5,
    const float* __restrict__ conv_b, unsigned short* __restrict__ hcbb)
{
    __shared__ float hs[68][68];
    __shared__ float wt[64][64];
    int e = blockIdx.y;
    const float* w = (e == 0) ? cw1 : ((e == 1) ? cw3 : cw5);
    int ksz = (e == 0) ? 1 : ((e == 1) ? 3 : 5);
    const float* h = hall + (long)e * NRT * RR_;
    unsigned short* hcb = hcbb + (long)e * NRT * RR_;
    const float* cb = conv_b + e * 64;
    int b = blockIdx.x & 15;
    int m0 = (blockIdx.x >> 4) * 64;
    int tid = threadIdx.x;
    int pad = (ksz - 1) >> 1;
    for (int idx = tid; idx < 68 * 16; idx += 256) {
        int mr = idx >> 4, i4 = idx & 15;
        int mm = m0 - 2 + mr;
        float4 vv = { 0.f, 0.f, 0.f, 0.f };
        if (mm >= 0 && mm < LT) vv = *(const float4*)(h + ((long)b * LT + mm) * RR_ + i4 * 4);
        *(float4*)&hs[mr][i4 * 4] = vv;
    }
    int tx = tid & 15, ty = tid >> 4;
    float acc[4][4] = {};
    for (int t = 0; t < ksz; t++) {
        __syncthreads();
        for (int idx = tid; idx < 4096; idx += 256) {
            int i = idx & 63, j = idx >> 6;
            wt[i][j] = w[(long)j * RR_ * ksz + i * ksz + t];
        }
        __syncthreads();
        int roff = ty * 4 + 2 + t - pad;
        for (int i4 = 0; i4 < 16; i4++) {
            float4 h0 = *(const float4*)&hs[roff + 0][i4 * 4];
            float4 h1 = *(const float4*)&hs[roff + 1][i4 * 4];
            float4 h2 = *(const float4*)&hs[roff + 2][i4 * 4];
            float4 h3 = *(const float4*)&hs[roff + 3][i4 * 4];
            float hh[4][4] = { { h0.x, h0.y, h0.z, h0.w }, { h1.x, h1.y, h1.z, h1.w },
                               { h2.x, h2.y, h2.z, h2.w }, { h3.x, h3.y, h3.z, h3.w } };
#pragma unroll
            for (int s = 0; s < 4; s++) {
                float4 wv = *(const float4*)&wt[i4 * 4 + s][tx * 4];
#pragma unroll
                for (int r = 0; r < 4; r++) {
                    acc[r][0] += hh[r][s] * wv.x;
                    acc[r][1] += hh[r][s] * wv.y;
                    acc[r][2] += hh[r][s] * wv.z;
                    acc[r][3] += hh[r][s] * wv.w;
                }
            }
        }
    }
    float4 bb = *(const float4*)(cb + tx * 4);
#pragma unroll
    for (int r = 0; r < 4; r++) {
        long m = (long)b * LT + m0 + ty * 4 + r;
        unsigned long long pv =
              (unsigned long long)cvt_pk_bf16(gelu_f(acc[r][0] + bb.x), gelu_f(acc[r][1] + bb.y))
            | ((unsigned long long)cvt_pk_bf16(gelu_f(acc[r][2] + bb.z), gelu_f(acc[r][3] + bb.w)) << 32);
        *(unsigned long long*)(hcb + m * RR_ + tx * 4) = pv;
    }
}

// ---------------- K8c: all 3 experts: up-proj + resid(bf16) + LN + gated sum ----------------
__global__ __launch_bounds__(256) void k_up3(
    const unsigned short* __restrict__ hcbb, const unsigned short* __restrict__ uWb,
    const float* __restrict__ up_b, const unsigned short* __restrict__ residb,
    const float* __restrict__ en_g, const float* __restrict__ en_b,
    const float* __restrict__ G, float* __restrict__ out)
{
    __shared__ short hs[64][88];
    __shared__ short Bs[256][40];
    int tid = threadIdx.x;
    int b = blockIdx.x & 15;
    int mseg = blockIdx.x >> 4;
    long row0 = (long)b * LT + mseg * 64;
    int wid = tid >> 6, lane = tid & 63;
    int l15 = lane & 15, kq = lane >> 4;
    int m_local = wid * 16;
    long mrow[4];
#pragma unroll
    for (int r = 0; r < 4; r++) mrow[r] = row0 + m_local + kq * 4 + r;
    f32x4 outacc[16];
#pragma unroll
    for (int j = 0; j < 16; j++) outacc[j] = (f32x4){0.f, 0.f, 0.f, 0.f};
    for (int e = 0; e < 3; e++) {
        __syncthreads();   // prior expert's LDS readers done
        const unsigned short* hcb = hcbb + (long)e * NRT * RR_;
        const unsigned short* uWe = uWb + (long)e * 16384;
#pragma unroll
        for (int hh = 0; hh < 2; hh++) {
            int idx = tid + 256 * hh;
            int row = idx >> 3, ch = idx & 7;
            *(int4*)&hs[row][ch * 8] = *(const int4*)(hcb + (row0 + row) * RR_ + ch * 8);
        }
        f32x4 acc[16];
#pragma unroll
        for (int j = 0; j < 16; j++) acc[j] = (f32x4){0.f, 0.f, 0.f, 0.f};
        for (int kt = 0; kt < 2; kt++) {
            int k0 = kt * 32;
#pragma unroll
            for (int hh = 0; hh < 4; hh++) {
                int idx = tid + 256 * hh;
                int n = idx >> 2, qc = idx & 3;
                *(int4*)&Bs[n][qc * 8] = *(const int4*)(uWe + (long)n * RR_ + k0 + qc * 8);
            }
            __syncthreads();
            bf16x8 af = *(const bf16x8*)&hs[m_local + l15][k0 + kq * 8];
#pragma unroll
            for (int j = 0; j < 16; j++) {
                bf16x8 bf = *(const bf16x8*)&Bs[j * 16 + l15][kq * 8];
                acc[j] = __builtin_amdgcn_mfma_f32_16x16x32_bf16(af, bf, acc[j], 0, 0, 0);
            }
            __syncthreads();
        }
        const float* ub = up_b + e * 256;
#pragma unroll
        for (int j = 0; j < 16; j++) {
            int col = j * 16 + l15;
            float bv = ub[col];
#pragma unroll
            for (int r = 0; r < 4; r++)
                acc[j][r] += bv + bf2f(residb[mrow[r] * D_ + col]);
        }
        float s[4] = {0.f, 0.f, 0.f, 0.f};
#pragma unroll
        for (int j = 0; j < 16; j++)
#pragma unroll
            for (int r = 0; r < 4; r++) s[r] += acc[j][r];
#pragma unroll
        for (int off = 8; off >= 1; off >>= 1)
#pragma unroll
            for (int r = 0; r < 4; r++) s[r] += __shfl_xor(s[r], off);
        float mn[4];
#pragma unroll
        for (int r = 0; r < 4; r++) mn[r] = s[r] * (1.0f / 256.0f);
        float q[4] = {0.f, 0.f, 0.f, 0.f};
#pragma unroll
        for (int j = 0; j < 16; j++)
#pragma unroll
            for (int r = 0; r < 4; r++) { float d = acc[j][r] - mn[r]; q[r] += d * d; }
#pragma unroll
        for (int off = 8; off >= 1; off >>= 1)
#pragma unroll
            for (int r = 0; r < 4; r++) q[r] += __shfl_xor(q[r], off);
        float iv[4], gv[4];
#pragma unroll
        for (int r = 0; r < 4; r++) {
            iv[r] = rsqrtf(q[r] * (1.0f / 256.0f) + 1e-5f);
            gv[r] = G[(long)e * NRT + mrow[r]];
        }
        const float* eg = en_g + e * 256;
        const float* eb = en_b + e * 256;
#pragma unroll
        for (int j = 0; j < 16; j++) {
            int col = j * 16 + l15;
            float egc = eg[col], ebc = eb[col];
#pragma unroll
            for (int r = 0; r < 4; r++)
                outacc[j][r] += gv[r] * ((acc[j][r] - mn[r]) * iv[r] * egc + ebc);
        }
    }
#pragma unroll
    for (int j = 0; j < 16; j++) {
        int col = j * 16 + l15;
#pragma unroll
        for (int r = 0; r < 4; r++)
            out[mrow[r] * D_ + col] = outacc[j][r];
    }
}

extern "C" void kernel_launch(void* const* d_in, const int* in_sizes, int n_in,
                              void* d_out, int out_size, void* d_ws, size_t ws_size,
                              hipStream_t stream)
{
    const float* text   = (const float*)d_in[0];
    const float* audio  = (const float*)d_in[1];
    const float* ln_g   = (const float*)d_in[2];
    const float* ln_b   = (const float*)d_in[3];
    const float* W_sh   = (const float*)d_in[4];
    const float* b_sh   = (const float*)d_in[5];
    const float* Wr1    = (const float*)d_in[6];
    const float* br1    = (const float*)d_in[7];
    const float* Wr2    = (const float*)d_in[8];
    const float* br2    = (const float*)d_in[9];
    const float* down_W = (const float*)d_in[10];
    const float* down_b = (const float*)d_in[11];
    const float* cw1    = (const float*)d_in[12];
    const float* cw3    = (const float*)d_in[13];
    const float* cw5    = (const float*)d_in[14];
    const float* conv_b = (const float*)d_in[15];
    const float* up_W   = (const float*)d_in[16];
    const float* up_b   = (const float*)d_in[17];
    const float* en_g   = (const float*)d_in[18];
    const float* en_b   = (const float*)d_in[19];

    float* ws = (float*)d_ws;
    float*          Tp    = ws;                               // 4,194,304 f
    unsigned short* Tnb   = (unsigned short*)(ws + 4194304);  // 2,097,152 f
    unsigned short* Anb   = (unsigned short*)(ws + 6291456);  // 4,194,304 f
    unsigned short* ApbT  = (unsigned short*)(ws + 10485760); // 4,194,304 f  (plain Ap^T bf16)
    unsigned char*  logK8 = (unsigned char*)(ws + 14680064);  // 8,388,608 f (33.5 MB u8)
    unsigned short* Apart = (unsigned short*)(ws + 23068672); // 2 x bf16 halves (16 MB of region)
    unsigned short* residb= (unsigned short*)(ws + 35651584); // 2,097,152 f
    float*          lu2   = ws + 37748736;                    // 16,384  (log2-domain)
    float*          lv2   = ws + 37765120;                    // 32,768  (log2-domain)
    float*          Sb    = ws + 37797888;                    // 16,384
    float*          Gb    = ws + 37814272;                    // 49,152
    unsigned short* Wb    = (unsigned short*)(ws + 37863424); // 32,768 f
    unsigned short* dWb   = (unsigned short*)(ws + 37896192); // 24,576 f
    unsigned short* uWb   = (unsigned short*)(ws + 37920768); // 24,576 f
    unsigned short* Wr1b  = (unsigned short*)(ws + 37945344); // 32,768 f
    size_t need_bytes = (size_t)37978112 * 4;
    if (ws_size < need_bytes) {
        fprintf(stderr, "kernel_launch: ws_size %zu < needed %zu\n", ws_size, need_bytes);
        return;
    }
    // aliases in logK8 region (dead after k_pi2):
    float*          hall = ws + 14680064;                     // 3,145,728 f
    unsigned short* hcbb = (unsigned short*)(ws + 17825792);  // 1,572,864 f
    // logK8T aliases the Apart region (33,554,432 B): written by k_cost_mfma, read by
    // k_collse4 x10, dead before k_pi2 writes Apart (stream-ordered).
    unsigned char*  logK8T = (unsigned char*)(ws + 23068672);

    k_prep_all<<<896, 256, 0, stream>>>(W_sh, down_W, up_W, Wr1, Wb, dWb, uWb, Wr1b);
    k_lnproj_fused<<<(NRT + NRA) / 64, 256, 0, stream>>>(text, audio, ln_g, ln_b, Wb, b_sh,
                                                         Tp, Tnb, Anb, ApbT);
    k_cost_mfma<<<dim3(NB, LT / 128, LA / 128), 256, 0, stream>>>(Tnb, Anb, logK8, logK8T);
    for (int it = 0; it < 10; it++) {
        k_rowlse4<<<NRT / 8, 256, 0, stream>>>(logK8, lv2, lu2, it == 0 ? 1 : 0);
        k_collse4<<<NB * (LA / 16), 256, 0, stream>>>(logK8T, lu2, lv2);
    }
    k_pi2<<<dim3(NB, 2, LT / 64), 256, 0, stream>>>(logK8, ApbT, lu2, lv2, Apart);
    k_sresid<<<NRT, 256, 0, stream>>>(Tp, Apart, residb, Sb);
    k_router_fused<<<NRT / 16, 256, 0, stream>>>(residb, Wr1b, Wr1, br1, Sb, Wr2, br2, Gb);
    k_down_mfma<<<dim3(NRT / 64, 3), 256, 0, stream>>>(residb, dWb, down_b, hall);
    k_conv_all<<<dim3(NRT / 64, 3), 256, 0, stream>>>(hall, cw1, cw3, cw5, conv_b, hcbb);
    k_up3<<<NRT / 64, 256, 0, stream>>>(hcbb, uWb, up_b, residb, en_g, en_b, Gb, (float*)d_out);
}